// Round 2
// baseline (2116.469 us; speedup 1.0000x reference)
//
#include <hip/hip_runtime.h>
#include <math.h>

// Problem constants
#define Bsz 16
#define Nn  1024
#define Ee  128
#define CTX 384
#define DIN 768
#define DST 16
#define DTR 24
#define ROWS (Bsz*Nn)   // 16384

// ---------------------------------------------------------------------------
// RMS row scales over the virtual ctx = [graph_emb(256) | node_emb(128)]
// ---------------------------------------------------------------------------
__global__ __launch_bounds__(128) void rms_k(
    const float* __restrict__ ge, const float* __restrict__ ne,
    float* __restrict__ rs)
{
    int row = blockIdx.x;            // b*1024 + n
    int b = row >> 10;
    int tid = threadIdx.x;
    float ssq = 0.f;
    #pragma unroll
    for (int k = 0; k < 3; ++k) {
        int idx = tid + k * 128;
        float v = (idx < 256) ? ge[b * 256 + idx]
                              : ne[(long long)row * 128 + (idx - 256)];
        ssq += v * v;
    }
    __shared__ float sh[128];
    sh[tid] = ssq;
    __syncthreads();
    for (int w = 64; w > 0; w >>= 1) {
        if (tid < w) sh[tid] += sh[tid + w];
        __syncthreads();
    }
    if (tid == 0) rs[row] = rsqrtf(sh[0] * (1.f / 384.f) + 1e-6f);
}

__global__ __launch_bounds__(256) void zero_k(float* __restrict__ p, int n)
{
    int i = blockIdx.x * 256 + threadIdx.x;
    if (i < n) p[i] = 0.f;
}

// ---------------------------------------------------------------------------
// Generic fp32 tiled GEMM: C[M,N] = A[M,K] @ B[K,N]  (B stored [N,K] when BT).
// 64x64 tile, BK=16, 256 thr, 4x4/thread.
// AMODE: 0 = plain A load; 1 = A composed from [ge|ne] * rs[row] * rms_w[col]
// EPI: 0 store, 1 softplus(acc+bias[col]), 3 acc+add (batched),
//      4 acc + ctx residual from [ge|ne]
// ---------------------------------------------------------------------------
template<int EPI, bool BT, int AMODE>
__global__ __launch_bounds__(256) void gemm_k(
    const float* __restrict__ A, int lda, long long aB,
    const float* __restrict__ Bm, int ldb, long long bB,
    float* __restrict__ C, int ldc, long long cB,
    int M, int N, int K,
    const float* __restrict__ ge, const float* __restrict__ ne,
    const float* __restrict__ rowS, const float* __restrict__ colS,
    const float* __restrict__ bias,
    const float* __restrict__ add, long long addB)
{
    __shared__ float As[16][68];
    __shared__ float Bs[16][68];
    int tid = threadIdx.x;
    int tx = tid & 15, ty = tid >> 4;
    int gn0 = blockIdx.x * 64;
    int rowBase = blockIdx.y * 64;
    int bz = blockIdx.z;
    const float* Ab = A + (long long)bz * aB + (long long)rowBase * lda;
    const float* Bb = Bm + (long long)bz * bB;
    float acc[4][4] = {};

    for (int k0 = 0; k0 < K; k0 += 16) {
        #pragma unroll
        for (int r = 0; r < 4; ++r) {
            int idx = tid + r * 256;
            int m = idx >> 4, kk = idx & 15;
            float v = 0.f;
            if (AMODE == 0) {
                if (k0 + kk < K) v = Ab[(long long)m * lda + k0 + kk];
            } else {
                int grow = rowBase + m;
                int col = k0 + kk;
                if (col < K) {
                    v = (col < 256) ? ge[(grow >> 10) * 256 + col]
                                    : ne[(long long)grow * 128 + (col - 256)];
                    v *= rowS[grow] * colS[col];
                }
            }
            As[kk][m] = v;
        }
        #pragma unroll
        for (int r = 0; r < 4; ++r) {
            int idx = tid + r * 256;
            if (!BT) {
                int n = idx & 63, kk = idx >> 6;
                float v = 0.f;
                if (k0 + kk < K && gn0 + n < N)
                    v = Bb[(long long)(k0 + kk) * ldb + gn0 + n];
                Bs[kk][n] = v;
            } else {
                int kk = idx & 15, n = idx >> 4;
                float v = 0.f;
                if (k0 + kk < K && gn0 + n < N)
                    v = Bb[(long long)(gn0 + n) * ldb + k0 + kk];
                Bs[kk][n] = v;
            }
        }
        __syncthreads();
        #pragma unroll
        for (int kk = 0; kk < 16; ++kk) {
            float4 a4 = *(const float4*)&As[kk][ty * 4];
            float4 b4 = *(const float4*)&Bs[kk][tx * 4];
            float av[4] = {a4.x, a4.y, a4.z, a4.w};
            float bv[4] = {b4.x, b4.y, b4.z, b4.w};
            #pragma unroll
            for (int i = 0; i < 4; ++i)
                #pragma unroll
                for (int j = 0; j < 4; ++j)
                    acc[i][j] = fmaf(av[i], bv[j], acc[i][j]);
        }
        __syncthreads();
    }

    #pragma unroll
    for (int i = 0; i < 4; ++i) {
        int gm = rowBase + ty * 4 + i;
        #pragma unroll
        for (int j = 0; j < 4; ++j) {
            int gn = gn0 + tx * 4 + j;
            if (gn >= N) continue;
            float v = acc[i][j];
            if (EPI == 1) {
                float x = v + bias[gn];
                v = fmaxf(x, 0.f) + log1pf(expf(-fabsf(x)));
            } else if (EPI == 3) {
                v += add[(long long)bz * addB + (long long)gm * (long long)N + gn];
            } else if (EPI == 4) {
                v += (gn < 256) ? ge[(gm >> 10) * 256 + gn]
                                : ne[(long long)gm * 128 + (gn - 256)];
            }
            C[(long long)bz * cB + (long long)gm * ldc + gn] = v;
        }
    }
}

// ---------------------------------------------------------------------------
// Depthwise causal conv (K=4) + bias + SiLU.  uB: [ROWS][768] -> ucv
// ---------------------------------------------------------------------------
__global__ __launch_bounds__(256) void conv_silu_k(
    const float* __restrict__ uB, const float* __restrict__ cw,
    const float* __restrict__ cb, float* __restrict__ ucv)
{
    long long idx = (long long)blockIdx.x * 256 + threadIdx.x; // < 16384*768
    int d = (int)(idx % 768);
    long long row = idx / 768;
    int n = (int)(row & 1023);
    float acc = cb[d];
    #pragma unroll
    for (int k = 0; k < 4; ++k) {
        int nn = n - 3 + k;
        if (nn >= 0)
            acc = fmaf(uB[idx + (long long)(nn - n) * 768], cw[d * 4 + k], acc);
    }
    float sig = 1.f / (1.f + expf(-acc));
    ucv[idx] = acc * sig;
}

// ---------------------------------------------------------------------------
// S6 scan. thread = (b, d, s); 16-lane groups reduce over DST states.
// Fused: y = (ys + Dp*u) * silu(z).  yG may alias u (in-place): each channel's
// u[n] is loaded one step before y[n] is stored, and channels don't overlap.
// ---------------------------------------------------------------------------
__global__ __launch_bounds__(256) void scan_k(
    const float* __restrict__ delta, const float* u,
    const float* __restrict__ dbc, const float* __restrict__ zB,
    const float* __restrict__ A_log, const float* __restrict__ Dp,
    float* yG)
{
    int tid = threadIdx.x;
    int s = tid & 15, dl = tid >> 4;
    int b = blockIdx.y;
    int d = blockIdx.x * 16 + dl;
    float a = -expf(A_log[d * 16 + s]);
    float dp = Dp[d];
    float h = 0.f;
    long long row0 = (long long)b * 1024;
    long long off = row0 * 768 + d;
    long long offb = row0 * 56;
    float dv = delta[off], uv = u[off];
    float Bv = dbc[offb + 24 + s], Cv = dbc[offb + 40 + s];
    for (int n = 0; n < 1024; ++n) {
        float dv_n = 0.f, uv_n = 0.f, Bv_n = 0.f, Cv_n = 0.f;
        if (n < 1023) {
            dv_n = delta[off + 768];
            uv_n = u[off + 768];
            Bv_n = dbc[offb + 56 + 24 + s];
            Cv_n = dbc[offb + 56 + 40 + s];
        }
        float dA = expf(dv * a);
        h = fmaf(dA, h, dv * uv * Bv);
        float yp = h * Cv;
        yp += __shfl_down(yp, 8, 16);
        yp += __shfl_down(yp, 4, 16);
        yp += __shfl_down(yp, 2, 16);
        yp += __shfl_down(yp, 1, 16);
        if (s == 0) {
            long long rr = row0 + n;
            float z = zB[rr * 768 + d];
            float sig = 1.f / (1.f + expf(-z));
            yG[off] = (yp + dp * uv) * (z * sig);
        }
        off += 768; offb += 56;
        dv = dv_n; uv = uv_n; Bv = Bv_n; Cv = Cv_n;
    }
}

// ---------------------------------------------------------------------------
// Sinkhorn half-iterations on la = la0 - R_i - C_j (never materialized).
// ---------------------------------------------------------------------------
__global__ __launch_bounds__(256) void col_lse_part(
    const float* __restrict__ la0, const float* __restrict__ R,
    float2* __restrict__ cpart)
{
    int j = blockIdx.x * 256 + threadIdx.x;
    int ch = blockIdx.y;   // 16 chunks of 64 i's
    int b = blockIdx.z;
    const float* base = la0 + (long long)b * 1024 * 1024 + (long long)ch * 64 * 1024 + j;
    const float* Rb = R + b * 1024 + ch * 64;
    float m = -INFINITY, sum = 0.f;
    for (int i = 0; i < 64; ++i) {
        float x = base[(long long)i * 1024] - Rb[i];
        float nm = fmaxf(m, x);
        sum = sum * expf(m - nm) + expf(x - nm);
        m = nm;
    }
    cpart[(long long)(b * 16 + ch) * 1024 + j] = make_float2(m, sum);
}

__global__ __launch_bounds__(256) void col_comb_k(
    const float2* __restrict__ cpart, float* __restrict__ Cv)
{
    int idx = blockIdx.x * 256 + threadIdx.x;   // b*1024 + j
    int b = idx >> 10, j = idx & 1023;
    float m = -INFINITY, sum = 0.f;
    #pragma unroll
    for (int ch = 0; ch < 16; ++ch) {
        float2 p = cpart[(long long)(b * 16 + ch) * 1024 + j];
        float nm = fmaxf(m, p.x);
        sum = sum * expf(m - nm) + p.y * expf(p.x - nm);
        m = nm;
    }
    Cv[idx] = m + logf(sum);
}

__global__ __launch_bounds__(256) void row_lse_k(
    const float* __restrict__ la0, const float* __restrict__ Cv,
    float* __restrict__ R)
{
    int r = blockIdx.x;
    int b = r >> 10;
    const float* row = la0 + (long long)r * 1024;
    const float* Cb = Cv + b * 1024;
    int tid = threadIdx.x;
    float m = -INFINITY, sum = 0.f;
    #pragma unroll
    for (int k = 0; k < 4; ++k) {
        int j = tid + k * 256;
        float x = row[j] - Cb[j];
        float nm = fmaxf(m, x);
        sum = sum * expf(m - nm) + expf(x - nm);
        m = nm;
    }
    __shared__ float sm[256], ss[256];
    sm[tid] = m; ss[tid] = sum;
    __syncthreads();
    for (int w = 128; w > 0; w >>= 1) {
        if (tid < w) {
            float m2 = sm[tid + w], s2 = ss[tid + w];
            float nm = fmaxf(sm[tid], m2);
            ss[tid] = ss[tid] * expf(sm[tid] - nm) + s2 * expf(m2 - nm);
            sm[tid] = nm;
        }
        __syncthreads();
    }
    if (tid == 0) R[r] = sm[0] + logf(ss[0]);
}

// ---------------------------------------------------------------------------
// Final: argmax(la+gumbel) (first-index ties), log_prob, entropy.
// out layout: tours[16384] | log_probs[16384] | entropies[16384] (all fp32)
// ---------------------------------------------------------------------------
__global__ __launch_bounds__(256) void final_k(
    const float* __restrict__ la0, const float* __restrict__ R,
    const float* __restrict__ Cv, const float* __restrict__ gs,
    float* __restrict__ out)
{
    int r = blockIdx.x;
    int b = r >> 10;
    const float* row = la0 + (long long)r * 1024;
    const float* gr = gs + (long long)r * 1024;
    const float* Cb = Cv + b * 1024;
    float Rvv = R[r];
    int tid = threadIdx.x;
    float bestg = -INFINITY;
    int bestj = 1 << 30;
    float ent = 0.f;
    #pragma unroll
    for (int k = 0; k < 4; ++k) {
        int j = tid + k * 256;
        float la = row[j] - Rvv - Cb[j];
        ent += la * expf(la);
        float g = la + gr[j];
        if (g > bestg || (g == bestg && j < bestj)) { bestg = g; bestj = j; }
    }
    __shared__ float sg[256]; __shared__ int sj[256]; __shared__ float se[256];
    sg[tid] = bestg; sj[tid] = bestj; se[tid] = ent;
    __syncthreads();
    for (int w = 128; w > 0; w >>= 1) {
        if (tid < w) {
            se[tid] += se[tid + w];
            float g2 = sg[tid + w]; int j2 = sj[tid + w];
            if (g2 > sg[tid] || (g2 == sg[tid] && j2 < sj[tid])) {
                sg[tid] = g2; sj[tid] = j2;
            }
        }
        __syncthreads();
    }
    if (tid == 0) {
        int j = sj[0];
        out[r] = (float)j;
        out[16384 + r] = row[j] - Rvv - Cb[j];
        out[32768 + r] = -se[0];
    }
}

// ---------------------------------------------------------------------------
extern "C" void kernel_launch(void* const* d_in, const int* in_sizes, int n_in,
                              void* d_out, int out_size, void* d_ws, size_t ws_size,
                              hipStream_t stream)
{
    const float* graph_emb = (const float*)d_in[0];
    const float* node_emb  = (const float*)d_in[1];
    const float* W_key     = (const float*)d_in[2];
    const float* rms_w     = (const float*)d_in[3];
    const float* W_in      = (const float*)d_in[4];
    const float* conv_w    = (const float*)d_in[5];
    const float* conv_b    = (const float*)d_in[6];
    const float* W_x       = (const float*)d_in[7];
    const float* W_dt      = (const float*)d_in[8];
    const float* b_dt      = (const float*)d_in[9];
    const float* A_log     = (const float*)d_in[10];
    const float* Dp        = (const float*)d_in[11];
    const float* W_out     = (const float*)d_in[12];
    const float* g_sink    = (const float*)d_in[13];
    const float* g_samp    = (const float*)d_in[14];
    float* out = (float*)d_out;

    // Workspace layout (floats). Total = 45,531,136 floats = 182.1 MB.
    float* ws = (float*)d_ws;
    size_t o = 0;
    auto alloc = [&](size_t nf) { float* p = ws + o; o += nf; return p; };
    float* rs    = alloc(ROWS);                    // 16K
    float* dbc   = alloc((size_t)ROWS * 56);       // 0.92M
    float* keys  = alloc((size_t)ROWS * 384);      // 6.29M
    float* uB    = alloc((size_t)ROWS * 768);      // 12.58M (delta aliases; la0 starts here)
    float* ucv   = alloc((size_t)ROWS * 768);      // 12.58M (yG aliases in-place; la0 spills here)
    float* zB    = alloc((size_t)ROWS * 768);      // 12.58M (queries aliases)
    float* Rv    = alloc(ROWS);
    float* Cvec  = alloc(ROWS);
    float* cpart = alloc((size_t)16 * 16 * 1024 * 2);
    float* delta   = uB;     // uB dead after conv
    float* queries = zB;     // zB dead after scan (needs 6.29M of 12.58M)
    float* la0     = uB;     // uB+ucv contiguous span 25.17M >= 16.78M

    // 1. RMS row scales over virtual ctx
    rms_k<<<dim3(ROWS), 128, 0, stream>>>(graph_emb, node_emb, rs);

    // 2. keys = node_emb @ W_key       (16384 x 384 x 128)
    gemm_k<0, false, 0><<<dim3(6, 256, 1), 256, 0, stream>>>(
        node_emb, 128, 0, W_key, 384, 0, keys, 384, 0,
        ROWS, 384, 128, nullptr, nullptr, nullptr, nullptr, nullptr, nullptr, 0);

    // 3a. uB = rmsnorm(ctx) @ W_in[:, :768]   (16384 x 768 x 384)
    gemm_k<0, false, 1><<<dim3(12, 256, 1), 256, 0, stream>>>(
        nullptr, 0, 0, W_in, 1536, 0, uB, 768, 0,
        ROWS, 768, 384, graph_emb, node_emb, rs, rms_w, nullptr, nullptr, 0);

    // 3b. zB = rmsnorm(ctx) @ W_in[:, 768:]   (16384 x 768 x 384)
    gemm_k<0, false, 1><<<dim3(12, 256, 1), 256, 0, stream>>>(
        nullptr, 0, 0, W_in + 768, 1536, 0, zB, 768, 0,
        ROWS, 768, 384, graph_emb, node_emb, rs, rms_w, nullptr, nullptr, 0);

    // 4. causal depthwise conv + silu: ucv = silu(conv(uB) + cb)
    conv_silu_k<<<dim3(ROWS * 768 / 256), 256, 0, stream>>>(uB, conv_w, conv_b, ucv);

    // 5. dbc = ucv @ W_x               (16384 x 56 x 768)
    gemm_k<0, false, 0><<<dim3(1, 256, 1), 256, 0, stream>>>(
        ucv, 768, 0, W_x, 56, 0, dbc, 56, 0,
        ROWS, 56, 768, nullptr, nullptr, nullptr, nullptr, nullptr, nullptr, 0);

    // 6. delta = softplus(dbc[:, :24] @ W_dt + b_dt)   (16384 x 768 x 24)
    gemm_k<1, false, 0><<<dim3(12, 256, 1), 256, 0, stream>>>(
        dbc, 56, 0, W_dt, 768, 0, delta, 768, 0,
        ROWS, 768, 24, nullptr, nullptr, nullptr, nullptr, b_dt, nullptr, 0);

    // 7. scan (fused: + Dp*u, *silu(z)); yG written in-place over ucv
    scan_k<<<dim3(48, 16), 256, 0, stream>>>(delta, ucv, dbc, zB, A_log, Dp, ucv);

    // 8. queries = ctx + yG @ W_out    (16384 x 384 x 768)
    gemm_k<4, false, 0><<<dim3(6, 256, 1), 256, 0, stream>>>(
        ucv, 768, 0, W_out, 384, 0, queries, 384, 0,
        ROWS, 384, 768, graph_emb, node_emb, nullptr, nullptr, nullptr, nullptr, 0);

    // 9. la0 = keys @ queries^T + gumbel_sink  (batched NT, 16 x 1024x1024x384)
    gemm_k<3, true, 0><<<dim3(16, 16, 16), 256, 0, stream>>>(
        keys, 384, (long long)Nn * 384, queries, 384, (long long)Nn * 384,
        la0, 1024, (long long)Nn * Nn,
        1024, 1024, 384, nullptr, nullptr, nullptr, nullptr, nullptr,
        g_sink, (long long)Nn * Nn);

    // 10. Sinkhorn: la = la0 - R_i - C_j, alternate LSE updates
    zero_k<<<dim3(64), 256, 0, stream>>>(Rv, ROWS);
    for (int it = 0; it < 5; ++it) {
        col_lse_part<<<dim3(4, 16, 16), 256, 0, stream>>>(la0, Rv, (float2*)cpart);
        col_comb_k<<<dim3(64), 256, 0, stream>>>((const float2*)cpart, Cvec);
        row_lse_k<<<dim3(ROWS), 256, 0, stream>>>(la0, Cvec, Rv);
    }

    // 11. outputs
    final_k<<<dim3(ROWS), 256, 0, stream>>>(la0, Rv, Cvec, g_samp, out);
}

// Round 3
// 1786.598 us; speedup vs baseline: 1.1846x; 1.1846x over previous
//
#include <hip/hip_runtime.h>
#include <math.h>

// Problem constants
#define Bsz 16
#define Nn  1024
#define Ee  128
#define CTX 384
#define DIN 768
#define DST 16
#define DTR 24
#define ROWS (Bsz*Nn)   // 16384

// ---------------------------------------------------------------------------
// RMS row scales over the virtual ctx = [graph_emb(256) | node_emb(128)]
// ---------------------------------------------------------------------------
__global__ __launch_bounds__(128) void rms_k(
    const float* __restrict__ ge, const float* __restrict__ ne,
    float* __restrict__ rs)
{
    int row = blockIdx.x;            // b*1024 + n
    int b = row >> 10;
    int tid = threadIdx.x;
    float ssq = 0.f;
    #pragma unroll
    for (int k = 0; k < 3; ++k) {
        int idx = tid + k * 128;
        float v = (idx < 256) ? ge[b * 256 + idx]
                              : ne[(long long)row * 128 + (idx - 256)];
        ssq += v * v;
    }
    __shared__ float sh[128];
    sh[tid] = ssq;
    __syncthreads();
    for (int w = 64; w > 0; w >>= 1) {
        if (tid < w) sh[tid] += sh[tid + w];
        __syncthreads();
    }
    if (tid == 0) rs[row] = rsqrtf(sh[0] * (1.f / 384.f) + 1e-6f);
}

__global__ __launch_bounds__(256) void zero_k(float* __restrict__ p, int n)
{
    int i = blockIdx.x * 256 + threadIdx.x;
    if (i < n) p[i] = 0.f;
}

// ---------------------------------------------------------------------------
// Generic fp32 tiled GEMM: C[M,N] = A[M,K] @ B[K,N]  (B stored [N,K] when BT).
// 64x64 tile, BK=16, 256 thr, 4x4/thread.
// AMODE: 0 = plain A[m*lda+k]; 1 = A composed from [ge|ne]*rs[row]*rms_w[col];
//        2 = A stored K-major: A[k*lda + m];
//        3 = K-major * silu(z) with z row-major [m*768+k] passed via rowS
// EPI: 0 store, 1 softplus(acc+bias[col]), 3 acc+add (batched),
//      4 acc + ctx residual from [ge|ne], 5 softplus(acc+bias[row])
// ---------------------------------------------------------------------------
template<int EPI, bool BT, int AMODE>
__global__ __launch_bounds__(256) void gemm_k(
    const float* __restrict__ A, int lda, long long aB,
    const float* __restrict__ Bm, int ldb, long long bB,
    float* __restrict__ C, int ldc, long long cB,
    int M, int N, int K,
    const float* __restrict__ ge, const float* __restrict__ ne,
    const float* __restrict__ rowS, const float* __restrict__ colS,
    const float* __restrict__ bias,
    const float* __restrict__ add, long long addB)
{
    __shared__ float As[16][68];
    __shared__ float Bs[16][68];
    int tid = threadIdx.x;
    int tx = tid & 15, ty = tid >> 4;
    int gn0 = blockIdx.x * 64;
    int rowBase = blockIdx.y * 64;
    int bz = blockIdx.z;
    const float* Ab = A + (long long)bz * aB + (long long)rowBase * lda;
    const float* Bb = Bm + (long long)bz * bB;
    float acc[4][4] = {};

    for (int k0 = 0; k0 < K; k0 += 16) {
        #pragma unroll
        for (int r = 0; r < 4; ++r) {
            int idx = tid + r * 256;
            int m = idx >> 4, kk = idx & 15;
            float v = 0.f;
            if (AMODE == 0) {
                if (k0 + kk < K) v = Ab[(long long)m * lda + k0 + kk];
            } else if (AMODE == 1) {
                int grow = rowBase + m;
                int col = k0 + kk;
                if (col < K) {
                    v = (col < 256) ? ge[(grow >> 10) * 256 + col]
                                    : ne[(long long)grow * 128 + (col - 256)];
                    v *= rowS[grow] * colS[col];
                }
            } else {
                int grow = rowBase + m;
                int col = k0 + kk;
                if (col < K) {
                    v = A[(long long)col * lda + grow];
                    if (AMODE == 3) {
                        float z = rowS[(long long)grow * 768 + col];
                        v *= z / (1.f + __expf(-z));
                    }
                }
            }
            As[kk][m] = v;
        }
        #pragma unroll
        for (int r = 0; r < 4; ++r) {
            int idx = tid + r * 256;
            if (!BT) {
                int n = idx & 63, kk = idx >> 6;
                float v = 0.f;
                if (k0 + kk < K && gn0 + n < N)
                    v = Bb[(long long)(k0 + kk) * ldb + gn0 + n];
                Bs[kk][n] = v;
            } else {
                int kk = idx & 15, n = idx >> 4;
                float v = 0.f;
                if (k0 + kk < K && gn0 + n < N)
                    v = Bb[(long long)(gn0 + n) * ldb + k0 + kk];
                Bs[kk][n] = v;
            }
        }
        __syncthreads();
        #pragma unroll
        for (int kk = 0; kk < 16; ++kk) {
            float4 a4 = *(const float4*)&As[kk][ty * 4];
            float4 b4 = *(const float4*)&Bs[kk][tx * 4];
            float av[4] = {a4.x, a4.y, a4.z, a4.w};
            float bv[4] = {b4.x, b4.y, b4.z, b4.w};
            #pragma unroll
            for (int i = 0; i < 4; ++i)
                #pragma unroll
                for (int j = 0; j < 4; ++j)
                    acc[i][j] = fmaf(av[i], bv[j], acc[i][j]);
        }
        __syncthreads();
    }

    #pragma unroll
    for (int i = 0; i < 4; ++i) {
        int gm = rowBase + ty * 4 + i;
        #pragma unroll
        for (int j = 0; j < 4; ++j) {
            int gn = gn0 + tx * 4 + j;
            if (gn >= N) continue;
            float v = acc[i][j];
            if (EPI == 1) {
                float x = v + bias[gn];
                v = fmaxf(x, 0.f) + log1pf(expf(-fabsf(x)));
            } else if (EPI == 3) {
                v += add[(long long)bz * addB + (long long)gm * (long long)N + gn];
            } else if (EPI == 4) {
                v += (gn < 256) ? ge[(gm >> 10) * 256 + gn]
                                : ne[(long long)gm * 128 + (gn - 256)];
            } else if (EPI == 5) {
                float x = v + bias[gm];
                v = fmaxf(x, 0.f) + log1pf(expf(-fabsf(x)));
            }
            C[(long long)bz * cB + (long long)gm * ldc + gn] = v;
        }
    }
}

// ---------------------------------------------------------------------------
// Depthwise causal conv (K=4) + bias + SiLU, writing TRANSPOSED output:
// uT[d][b*1024+n] from uB[(b*1024+n)*768+d]. LDS tile 67x32 (3-row halo).
// ---------------------------------------------------------------------------
__global__ __launch_bounds__(256) void conv_t_k(
    const float* __restrict__ uB, const float* __restrict__ cw,
    const float* __restrict__ cb, float* __restrict__ uT)
{
    __shared__ float tile[67][33];
    int b = blockIdx.z, d0 = blockIdx.y * 32, n0 = blockIdx.x * 64;
    int tid = threadIdx.x;
    for (int i = tid; i < 67 * 32; i += 256) {
        int r = i >> 5, c = i & 31;
        int n = n0 - 3 + r;
        tile[r][c] = (n >= 0) ? uB[((long long)(b * 1024 + n)) * 768 + d0 + c] : 0.f;
    }
    __syncthreads();
    int nl = tid & 63;
    int dh = (tid >> 6) * 8;
    #pragma unroll
    for (int dl = 0; dl < 8; ++dl) {
        int d = dh + dl;
        const float* w = cw + (d0 + d) * 4;
        float acc = cb[d0 + d];
        acc = fmaf(tile[nl][d],     w[0], acc);
        acc = fmaf(tile[nl + 1][d], w[1], acc);
        acc = fmaf(tile[nl + 2][d], w[2], acc);
        acc = fmaf(tile[nl + 3][d], w[3], acc);
        float sv = acc / (1.f + __expf(-acc));
        uT[(long long)(d0 + d) * 16384 + b * 1024 + n0 + nl] = sv;
    }
}

// ---------------------------------------------------------------------------
// Pack B/C columns of dbc into TBC[32][16384]: rows 0..15 = B(s), 16..31 = C(s)
// ---------------------------------------------------------------------------
__global__ __launch_bounds__(256) void pack_bc_k(
    const float* __restrict__ dbc, float* __restrict__ TBC)
{
    int c = blockIdx.y;
    int gm = blockIdx.x * 256 + threadIdx.x;
    TBC[(long long)c * 16384 + gm] = dbc[(long long)gm * 56 + 24 + c];
}

// ---------------------------------------------------------------------------
// S6 scan v2: all streams K-major (per-thread sequential). thread=(b,d,s),
// 16-lane groups reduce over states. Depth-2 float4 group prefetch.
// y written in-place over uT (row exclusive to this wave's 16-lane group).
// ---------------------------------------------------------------------------
__global__ __launch_bounds__(256) void scan2_k(
    const float* __restrict__ dT, float* uyT,
    const float* __restrict__ TBC, const float* __restrict__ A_log,
    const float* __restrict__ Dp)
{
    int tid = threadIdx.x;
    int s = tid & 15, dl = tid >> 4;
    int b = blockIdx.y;
    int d = blockIdx.x * 16 + dl;
    float a = -__expf(A_log[d * 16 + s]);
    float dp = Dp[d];
    long long base = (long long)b * 1024;
    const float* dR = dT + (long long)d * 16384 + base;
    const float* uR = uyT + (long long)d * 16384 + base;
    const float* BR = TBC + (long long)s * 16384 + base;
    const float* CR = TBC + (long long)(16 + s) * 16384 + base;
    float* yR = uyT + (long long)d * 16384 + base;

    float4 dv0 = *(const float4*)(dR);
    float4 dv1 = *(const float4*)(dR + 4);
    float4 uv0 = *(const float4*)(uR);
    float4 uv1 = *(const float4*)(uR + 4);
    float4 Bv0 = *(const float4*)(BR);
    float4 Bv1 = *(const float4*)(BR + 4);
    float4 Cv0 = *(const float4*)(CR);
    float4 Cv1 = *(const float4*)(CR + 4);
    float h = 0.f;

    for (int g = 0; g < 256; ++g) {
        int gp = (g + 2 < 256) ? (g + 2) * 4 : 255 * 4;
        float4 dv2 = *(const float4*)(dR + gp);
        float4 uv2 = *(const float4*)(uR + gp);
        float4 Bv2 = *(const float4*)(BR + gp);
        float4 Cv2 = *(const float4*)(CR + gp);

        float dv[4] = {dv0.x, dv0.y, dv0.z, dv0.w};
        float uv[4] = {uv0.x, uv0.y, uv0.z, uv0.w};
        float Bv[4] = {Bv0.x, Bv0.y, Bv0.z, Bv0.w};
        float Cv[4] = {Cv0.x, Cv0.y, Cv0.z, Cv0.w};
        float ya[4];
        #pragma unroll
        for (int j = 0; j < 4; ++j) {
            float dA = __expf(dv[j] * a);
            h = fmaf(dA, h, dv[j] * uv[j] * Bv[j]);
            float yp = h * Cv[j];
            yp += __shfl_down(yp, 8, 16);
            yp += __shfl_down(yp, 4, 16);
            yp += __shfl_down(yp, 2, 16);
            yp += __shfl_down(yp, 1, 16);
            ya[j] = yp + dp * uv[j];
        }
        if (s == 0) {
            *(float4*)(yR + g * 4) = make_float4(ya[0], ya[1], ya[2], ya[3]);
        }
        dv0 = dv1; dv1 = dv2;
        uv0 = uv1; uv1 = uv2;
        Bv0 = Bv1; Bv1 = Bv2;
        Cv0 = Cv1; Cv1 = Cv2;
    }
}

// ---------------------------------------------------------------------------
// Sinkhorn half-iterations on la = la0 - R_i - C_j (never materialized).
// ---------------------------------------------------------------------------
__global__ __launch_bounds__(256) void col_lse_part(
    const float* __restrict__ la0, const float* __restrict__ R,
    float2* __restrict__ cpart)
{
    int j = blockIdx.x * 256 + threadIdx.x;
    int ch = blockIdx.y;   // 16 chunks of 64 i's
    int b = blockIdx.z;
    const float* base = la0 + (long long)b * 1024 * 1024 + (long long)ch * 64 * 1024 + j;
    const float* Rb = R + b * 1024 + ch * 64;
    float m = -INFINITY, sum = 0.f;
    for (int i = 0; i < 64; ++i) {
        float x = base[(long long)i * 1024] - Rb[i];
        float nm = fmaxf(m, x);
        sum = sum * expf(m - nm) + expf(x - nm);
        m = nm;
    }
    cpart[(long long)(b * 16 + ch) * 1024 + j] = make_float2(m, sum);
}

__global__ __launch_bounds__(256) void col_comb_k(
    const float2* __restrict__ cpart, float* __restrict__ Cv)
{
    int idx = blockIdx.x * 256 + threadIdx.x;   // b*1024 + j
    int b = idx >> 10, j = idx & 1023;
    float m = -INFINITY, sum = 0.f;
    #pragma unroll
    for (int ch = 0; ch < 16; ++ch) {
        float2 p = cpart[(long long)(b * 16 + ch) * 1024 + j];
        float nm = fmaxf(m, p.x);
        sum = sum * expf(m - nm) + p.y * expf(p.x - nm);
        m = nm;
    }
    Cv[idx] = m + logf(sum);
}

__global__ __launch_bounds__(256) void row_lse_k(
    const float* __restrict__ la0, const float* __restrict__ Cv,
    float* __restrict__ R)
{
    int r = blockIdx.x;
    int b = r >> 10;
    const float* row = la0 + (long long)r * 1024;
    const float* Cb = Cv + b * 1024;
    int tid = threadIdx.x;
    float m = -INFINITY, sum = 0.f;
    #pragma unroll
    for (int k = 0; k < 4; ++k) {
        int j = tid + k * 256;
        float x = row[j] - Cb[j];
        float nm = fmaxf(m, x);
        sum = sum * expf(m - nm) + expf(x - nm);
        m = nm;
    }
    __shared__ float sm[256], ss[256];
    sm[tid] = m; ss[tid] = sum;
    __syncthreads();
    for (int w = 128; w > 0; w >>= 1) {
        if (tid < w) {
            float m2 = sm[tid + w], s2 = ss[tid + w];
            float nm = fmaxf(sm[tid], m2);
            ss[tid] = ss[tid] * expf(sm[tid] - nm) + s2 * expf(m2 - nm);
            sm[tid] = nm;
        }
        __syncthreads();
    }
    if (tid == 0) R[r] = sm[0] + logf(ss[0]);
}

// ---------------------------------------------------------------------------
// Final: argmax(la+gumbel) (first-index ties), log_prob, entropy.
// out layout: tours[16384] | log_probs[16384] | entropies[16384] (all fp32)
// ---------------------------------------------------------------------------
__global__ __launch_bounds__(256) void final_k(
    const float* __restrict__ la0, const float* __restrict__ R,
    const float* __restrict__ Cv, const float* __restrict__ gs,
    float* __restrict__ out)
{
    int r = blockIdx.x;
    int b = r >> 10;
    const float* row = la0 + (long long)r * 1024;
    const float* gr = gs + (long long)r * 1024;
    const float* Cb = Cv + b * 1024;
    float Rvv = R[r];
    int tid = threadIdx.x;
    float bestg = -INFINITY;
    int bestj = 1 << 30;
    float ent = 0.f;
    #pragma unroll
    for (int k = 0; k < 4; ++k) {
        int j = tid + k * 256;
        float la = row[j] - Rvv - Cb[j];
        ent += la * expf(la);
        float g = la + gr[j];
        if (g > bestg || (g == bestg && j < bestj)) { bestg = g; bestj = j; }
    }
    __shared__ float sg[256]; __shared__ int sj[256]; __shared__ float se[256];
    sg[tid] = bestg; sj[tid] = bestj; se[tid] = ent;
    __syncthreads();
    for (int w = 128; w > 0; w >>= 1) {
        if (tid < w) {
            se[tid] += se[tid + w];
            float g2 = sg[tid + w]; int j2 = sj[tid + w];
            if (g2 > sg[tid] || (g2 == sg[tid] && j2 < sj[tid])) {
                sg[tid] = g2; sj[tid] = j2;
            }
        }
        __syncthreads();
    }
    if (tid == 0) {
        int j = sj[0];
        out[r] = (float)j;
        out[16384 + r] = row[j] - Rvv - Cb[j];
        out[32768 + r] = -se[0];
    }
}

// ---------------------------------------------------------------------------
extern "C" void kernel_launch(void* const* d_in, const int* in_sizes, int n_in,
                              void* d_out, int out_size, void* d_ws, size_t ws_size,
                              hipStream_t stream)
{
    const float* graph_emb = (const float*)d_in[0];
    const float* node_emb  = (const float*)d_in[1];
    const float* W_key     = (const float*)d_in[2];
    const float* rms_w     = (const float*)d_in[3];
    const float* W_in      = (const float*)d_in[4];
    const float* conv_w    = (const float*)d_in[5];
    const float* conv_b    = (const float*)d_in[6];
    const float* W_x       = (const float*)d_in[7];
    const float* W_dt      = (const float*)d_in[8];
    const float* b_dt      = (const float*)d_in[9];
    const float* A_log     = (const float*)d_in[10];
    const float* Dp        = (const float*)d_in[11];
    const float* W_out     = (const float*)d_in[12];
    const float* g_sink    = (const float*)d_in[13];
    const float* g_samp    = (const float*)d_in[14];
    float* out = (float*)d_out;

    // Workspace layout (floats). Total = 45,531,136 floats = 182.1 MB
    // (identical footprint to the passing round-2 layout).
    float* ws = (float*)d_ws;
    size_t o = 0;
    auto alloc = [&](size_t nf) { float* p = ws + o; o += nf; return p; };
    float* rs    = alloc(ROWS);                    // 16K
    float* dbc   = alloc((size_t)ROWS * 56);       // 0.92M
    float* keys  = alloc((size_t)ROWS * 384);      // 6.29M
    float* R1    = alloc((size_t)ROWS * 768);      // uB -> deltaT -> queries
    float* R2    = alloc((size_t)ROWS * 768);      // uT -> yT (in-place); la0 starts here
    float* R3    = alloc((size_t)ROWS * 768);      // zB; la0 spills here
    float* Rv    = alloc(ROWS);
    float* Cvec  = alloc(ROWS);
    float* cpart = alloc((size_t)16 * 16 * 1024 * 2);  // aliased by TBC (disjoint lifetime)
    float* uB      = R1;
    float* deltaT  = R1;    // uB dead after conv
    float* queries = R1;    // deltaT dead after scan
    float* uT      = R2;    // also yT (scan writes in-place)
    float* zB      = R3;
    float* la0     = R2;    // R2+R3 span 25.17M >= 16.78M; yT/zB dead by then
    float* TBC     = cpart; // 32*16384 = 524288 = cpart size

    // 1. RMS row scales over virtual ctx
    rms_k<<<dim3(ROWS), 128, 0, stream>>>(graph_emb, node_emb, rs);

    // 2. keys = node_emb @ W_key       (16384 x 384 x 128)
    gemm_k<0, false, 0><<<dim3(6, 256, 1), 256, 0, stream>>>(
        node_emb, 128, 0, W_key, 384, 0, keys, 384, 0,
        ROWS, 384, 128, nullptr, nullptr, nullptr, nullptr, nullptr, nullptr, 0);

    // 3a. uB = rmsnorm(ctx) @ W_in[:, :768]   (16384 x 768 x 384)
    gemm_k<0, false, 1><<<dim3(12, 256, 1), 256, 0, stream>>>(
        nullptr, 0, 0, W_in, 1536, 0, uB, 768, 0,
        ROWS, 768, 384, graph_emb, node_emb, rs, rms_w, nullptr, nullptr, 0);

    // 3b. zB = rmsnorm(ctx) @ W_in[:, 768:]   (16384 x 768 x 384)
    gemm_k<0, false, 1><<<dim3(12, 256, 1), 256, 0, stream>>>(
        nullptr, 0, 0, W_in + 768, 1536, 0, zB, 768, 0,
        ROWS, 768, 384, graph_emb, node_emb, rs, rms_w, nullptr, nullptr, 0);

    // 4. causal depthwise conv + silu, transposed out: uT[d][b*1024+n]
    conv_t_k<<<dim3(16, 24, 16), 256, 0, stream>>>(uB, conv_w, conv_b, uT);

    // 5. dbc = u @ W_x  (A = uT, K-major)      (16384 x 56 x 768)
    gemm_k<0, false, 2><<<dim3(1, 256, 1), 256, 0, stream>>>(
        uT, 16384, 0, W_x, 56, 0, dbc, 56, 0,
        ROWS, 56, 768, nullptr, nullptr, nullptr, nullptr, nullptr, nullptr, 0);

    // 6. deltaT[768 x 16384] = softplus(W_dt^T @ dbc_dt^T + b_dt[row])
    //    A = W_dt (K-major, lda=768), B = dbc rows (BT, ldb=56), K=24
    gemm_k<5, true, 2><<<dim3(256, 12, 1), 256, 0, stream>>>(
        W_dt, 768, 0, dbc, 56, 0, deltaT, 16384, 0,
        768, 16384, 24, nullptr, nullptr, nullptr, nullptr, b_dt, nullptr, 0);

    // 7. pack B/C into TBC[32][16384]
    pack_bc_k<<<dim3(64, 32), 256, 0, stream>>>(dbc, TBC);

    // 8. scan v2 (fused + Dp*u); y written in-place over uT
    scan2_k<<<dim3(48, 16), 256, 0, stream>>>(deltaT, uT, TBC, A_log, Dp);

    // 9. queries = ctx + (y * silu(z)) @ W_out    (16384 x 384 x 768)
    //    A = yT (K-major) gated by silu(zB row-major via rowS)
    gemm_k<4, false, 3><<<dim3(6, 256, 1), 256, 0, stream>>>(
        uT, 16384, 0, W_out, 384, 0, queries, 384, 0,
        ROWS, 384, 768, graph_emb, node_emb, zB, nullptr, nullptr, nullptr, 0);

    // 10. la0 = keys @ queries^T + gumbel_sink  (batched NT, 16 x 1024x1024x384)
    gemm_k<3, true, 0><<<dim3(16, 16, 16), 256, 0, stream>>>(
        keys, 384, (long long)Nn * 384, queries, 384, (long long)Nn * 384,
        la0, 1024, (long long)Nn * Nn,
        1024, 1024, 384, nullptr, nullptr, nullptr, nullptr, nullptr,
        g_sink, (long long)Nn * Nn);

    // 11. Sinkhorn: la = la0 - R_i - C_j, alternate LSE updates
    zero_k<<<dim3(64), 256, 0, stream>>>(Rv, ROWS);
    for (int it = 0; it < 5; ++it) {
        col_lse_part<<<dim3(4, 16, 16), 256, 0, stream>>>(la0, Rv, (float2*)cpart);
        col_comb_k<<<dim3(64), 256, 0, stream>>>((const float2*)cpart, Cvec);
        row_lse_k<<<dim3(ROWS), 256, 0, stream>>>(la0, Cvec, Rv);
    }

    // 12. outputs
    final_k<<<dim3(ROWS), 256, 0, stream>>>(la0, Rv, Cvec, g_samp, out);
}

// Round 4
// 1604.022 us; speedup vs baseline: 1.3195x; 1.1138x over previous
//
#include <hip/hip_runtime.h>
#include <math.h>

// Problem constants
#define Bsz 16
#define Nn  1024
#define Ee  128
#define CTX 384
#define DIN 768
#define DST 16
#define DTR 24
#define ROWS (Bsz*Nn)   // 16384

// ---------------------------------------------------------------------------
// RMS row scales over the virtual ctx = [graph_emb(256) | node_emb(128)]
// ---------------------------------------------------------------------------
__global__ __launch_bounds__(128) void rms_k(
    const float* __restrict__ ge, const float* __restrict__ ne,
    float* __restrict__ rs)
{
    int row = blockIdx.x;            // b*1024 + n
    int b = row >> 10;
    int tid = threadIdx.x;
    float ssq = 0.f;
    #pragma unroll
    for (int k = 0; k < 3; ++k) {
        int idx = tid + k * 128;
        float v = (idx < 256) ? ge[b * 256 + idx]
                              : ne[(long long)row * 128 + (idx - 256)];
        ssq += v * v;
    }
    __shared__ float sh[128];
    sh[tid] = ssq;
    __syncthreads();
    for (int w = 64; w > 0; w >>= 1) {
        if (tid < w) sh[tid] += sh[tid + w];
        __syncthreads();
    }
    if (tid == 0) rs[row] = rsqrtf(sh[0] * (1.f / 384.f) + 1e-6f);
}

__global__ __launch_bounds__(256) void zero_k(float* __restrict__ p, int n)
{
    int i = blockIdx.x * 256 + threadIdx.x;
    if (i < n) p[i] = 0.f;
}

// ---------------------------------------------------------------------------
// gemm2: C[M,N] = A[M,K] @ B[K,N].  128x128 tile, BK=16, 256 thr, 8x8/thread.
// AMODE: 0 = A row-major [m*lda+k]; 1 = A composed from [ge|ne]*rs[m]*rms_w[k];
//        2 = A K-major [k*lda + m] (coalesced float4 along m)
// BT:    false = B row-major [k*ldb+n]; true = B stored [n*ldb+k] (transpose-load)
// CT:    true  = store C transposed: C[gn*ldc + gm] (EPI 0 only)
// EPI:   0 plain; 3 acc+add (batched); 4 acc + ctx residual; 5 softplus(acc+bias[row])
// ---------------------------------------------------------------------------
template<int EPI, bool BT, int AMODE, bool CT>
__global__ __launch_bounds__(256) void gemm2_k(
    const float* __restrict__ A, int lda, long long aB,
    const float* __restrict__ Bm, int ldb, long long bB,
    float* __restrict__ C, int ldc, long long cB,
    int M, int N, int K,
    const float* __restrict__ ge, const float* __restrict__ ne,
    const float* __restrict__ rowS, const float* __restrict__ colS,
    const float* __restrict__ bias,
    const float* __restrict__ add, long long addB)
{
    __shared__ float As[16][132];
    __shared__ float Bs[16][132];
    int t = threadIdx.x;
    int gn0 = blockIdx.x * 128;
    int rowBase = blockIdx.y * 128;
    int bz = blockIdx.z;
    const float* Abase = A + (long long)bz * aB;
    const float* Bb = Bm + (long long)bz * bB;
    float acc[8][8] = {};

    int cx4 = (t & 15) * 4;
    int ry4 = (t >> 4) * 4;

    for (int k0 = 0; k0 < K; k0 += 16) {
        // ---- load A tile -> As[kk][m] ----
        if (AMODE == 0 || AMODE == 1) {
            int r = t >> 1;              // 0..127
            int kq = (t & 1) * 8;        // 0 or 8
            float av[8];
            if (AMODE == 0) {
                const float* Ap = Abase + (long long)(rowBase + r) * lda + k0 + kq;
                #pragma unroll
                for (int j = 0; j < 8; ++j)
                    av[j] = (k0 + kq + j < K) ? Ap[j] : 0.f;
            } else {
                int grow = rowBase + r;
                float rsv = rowS[grow];
                #pragma unroll
                for (int j = 0; j < 8; ++j) {
                    int col = k0 + kq + j;
                    float v = 0.f;
                    if (col < K) {
                        v = (col < 256) ? ge[(grow >> 10) * 256 + col]
                                        : ne[(long long)grow * 128 + (col - 256)];
                        v *= rsv * colS[col];
                    }
                    av[j] = v;
                }
            }
            #pragma unroll
            for (int j = 0; j < 8; ++j) As[kq + j][r] = av[j];
        } else {
            int kk = t >> 4;             // 0..15
            int m0 = (t & 15) * 8;       // 0..120
            const float* Ap = Abase + (long long)(k0 + kk) * lda + rowBase + m0;
            float4 v0 = make_float4(0.f, 0.f, 0.f, 0.f), v1 = v0;
            if (k0 + kk < K) {
                v0 = *(const float4*)Ap;
                v1 = *(const float4*)(Ap + 4);
            }
            *(float4*)&As[kk][m0] = v0;
            *(float4*)&As[kk][m0 + 4] = v1;
        }
        // ---- load B tile -> Bs[kk][n] ----
        if (!BT) {
            int kk = t >> 4;
            int n0 = (t & 15) * 8;
            const float* Bp = Bb + (long long)(k0 + kk) * ldb + gn0 + n0;
            float4 v0 = make_float4(0.f, 0.f, 0.f, 0.f), v1 = v0;
            if (k0 + kk < K) {
                if (gn0 + n0 + 7 < N) {
                    v0 = *(const float4*)Bp;
                    v1 = *(const float4*)(Bp + 4);
                } else {
                    float tmp[8];
                    #pragma unroll
                    for (int j = 0; j < 8; ++j)
                        tmp[j] = (gn0 + n0 + j < N) ? Bp[j] : 0.f;
                    v0 = make_float4(tmp[0], tmp[1], tmp[2], tmp[3]);
                    v1 = make_float4(tmp[4], tmp[5], tmp[6], tmp[7]);
                }
            }
            *(float4*)&Bs[kk][n0] = v0;
            *(float4*)&Bs[kk][n0 + 4] = v1;
        } else {
            int n = t >> 1;
            int kq = (t & 1) * 8;
            const float* Bp = Bb + (long long)(gn0 + n) * ldb + k0 + kq;
            float bv[8];
            bool nok = (gn0 + n < N);
            #pragma unroll
            for (int j = 0; j < 8; ++j)
                bv[j] = (nok && k0 + kq + j < K) ? Bp[j] : 0.f;
            #pragma unroll
            for (int j = 0; j < 8; ++j) Bs[kq + j][n] = bv[j];
        }
        __syncthreads();
        // ---- compute ----
        #pragma unroll
        for (int kk = 0; kk < 16; ++kk) {
            float4 a0 = *(const float4*)&As[kk][ry4];
            float4 a1 = *(const float4*)&As[kk][ry4 + 64];
            float4 b0 = *(const float4*)&Bs[kk][cx4];
            float4 b1 = *(const float4*)&Bs[kk][cx4 + 64];
            float av[8] = {a0.x, a0.y, a0.z, a0.w, a1.x, a1.y, a1.z, a1.w};
            float bv[8] = {b0.x, b0.y, b0.z, b0.w, b1.x, b1.y, b1.z, b1.w};
            #pragma unroll
            for (int i = 0; i < 8; ++i)
                #pragma unroll
                for (int j = 0; j < 8; ++j)
                    acc[i][j] = fmaf(av[i], bv[j], acc[i][j]);
        }
        __syncthreads();
    }

    // ---- epilogue ----
    if (CT) {
        // transposed store (EPI 0): C[gn*ldc + gm]
        #pragma unroll
        for (int j = 0; j < 8; ++j) {
            int gn = gn0 + (j >> 2) * 64 + cx4 + (j & 3);
            #pragma unroll
            for (int ih = 0; ih < 2; ++ih) {
                int gmb = rowBase + ih * 64 + ry4;
                float4 v = make_float4(acc[ih * 4 + 0][j], acc[ih * 4 + 1][j],
                                       acc[ih * 4 + 2][j], acc[ih * 4 + 3][j]);
                *(float4*)&C[(long long)gn * ldc + gmb] = v;
            }
        }
    } else {
        float* Cb = C + (long long)bz * cB;
        #pragma unroll
        for (int i = 0; i < 8; ++i) {
            int gm = rowBase + (i >> 2) * 64 + ry4 + (i & 3);
            #pragma unroll
            for (int jh = 0; jh < 2; ++jh) {
                int gn = gn0 + jh * 64 + cx4;
                float v[4];
                #pragma unroll
                for (int e = 0; e < 4; ++e) {
                    float x = acc[i][jh * 4 + e];
                    if (EPI == 3) {
                        x += add[(long long)bz * addB + (long long)gm * (long long)N + gn + e];
                    } else if (EPI == 4) {
                        int c = gn + e;
                        x += (c < 256) ? ge[(gm >> 10) * 256 + c]
                                       : ne[(long long)gm * 128 + (c - 256)];
                    } else if (EPI == 5) {
                        float s = x + bias[gm];
                        x = fmaxf(s, 0.f) + log1pf(expf(-fabsf(s)));
                    }
                    v[e] = x;
                }
                if (gn + 3 < N) {
                    *(float4*)&Cb[(long long)gm * ldc + gn] =
                        make_float4(v[0], v[1], v[2], v[3]);
                } else {
                    #pragma unroll
                    for (int e = 0; e < 4; ++e)
                        if (gn + e < N) Cb[(long long)gm * ldc + gn + e] = v[e];
                }
            }
        }
    }
}

// ---------------------------------------------------------------------------
// Depthwise causal conv (K=4) + bias + SiLU, writing TRANSPOSED output:
// uT[d][b*1024+n] from uB[(b*1024+n)*768+d]. LDS tile 67x32 (3-row halo).
// ---------------------------------------------------------------------------
__global__ __launch_bounds__(256) void conv_t_k(
    const float* __restrict__ uB, const float* __restrict__ cw,
    const float* __restrict__ cb, float* __restrict__ uT)
{
    __shared__ float tile[67][33];
    int b = blockIdx.z, d0 = blockIdx.y * 32, n0 = blockIdx.x * 64;
    int tid = threadIdx.x;
    for (int i = tid; i < 67 * 32; i += 256) {
        int r = i >> 5, c = i & 31;
        int n = n0 - 3 + r;
        tile[r][c] = (n >= 0) ? uB[((long long)(b * 1024 + n)) * 768 + d0 + c] : 0.f;
    }
    __syncthreads();
    int nl = tid & 63;
    int dh = (tid >> 6) * 8;
    #pragma unroll
    for (int dl = 0; dl < 8; ++dl) {
        int d = dh + dl;
        const float* w = cw + (d0 + d) * 4;
        float acc = cb[d0 + d];
        acc = fmaf(tile[nl][d],     w[0], acc);
        acc = fmaf(tile[nl + 1][d], w[1], acc);
        acc = fmaf(tile[nl + 2][d], w[2], acc);
        acc = fmaf(tile[nl + 3][d], w[3], acc);
        float sv = acc / (1.f + __expf(-acc));
        uT[(long long)(d0 + d) * 16384 + b * 1024 + n0 + nl] = sv;
    }
}

// ---------------------------------------------------------------------------
// Pack B/C columns of dbc into TBC[32][16384]: rows 0..15 = B(s), 16..31 = C(s)
// ---------------------------------------------------------------------------
__global__ __launch_bounds__(256) void pack_bc_k(
    const float* __restrict__ dbc, float* __restrict__ TBC)
{
    int c = blockIdx.y;
    int gm = blockIdx.x * 256 + threadIdx.x;
    TBC[(long long)c * 16384 + gm] = dbc[(long long)gm * 56 + 24 + c];
}

// ---------------------------------------------------------------------------
// S6 scan v3: all streams K-major sequential. thread=(b,d,s), 16-lane groups
// reduce over states. Depth-2 float4 group prefetch. Output y is GATED:
// y = (ys + Dp*u) * silu(z), written in-place over uT.
// ---------------------------------------------------------------------------
__global__ __launch_bounds__(256) void scan3_k(
    const float* __restrict__ dT, float* uyT, const float* __restrict__ zT,
    const float* __restrict__ TBC, const float* __restrict__ A_log,
    const float* __restrict__ Dp)
{
    int tid = threadIdx.x;
    int s = tid & 15, dl = tid >> 4;
    int b = blockIdx.y;
    int d = blockIdx.x * 16 + dl;
    float a = -__expf(A_log[d * 16 + s]);
    float dp = Dp[d];
    long long base = (long long)b * 1024;
    const float* dR = dT + (long long)d * 16384 + base;
    const float* uR = uyT + (long long)d * 16384 + base;
    const float* zR = zT + (long long)d * 16384 + base;
    const float* BR = TBC + (long long)s * 16384 + base;
    const float* CR = TBC + (long long)(16 + s) * 16384 + base;
    float* yR = uyT + (long long)d * 16384 + base;

    float4 dv0 = *(const float4*)(dR);
    float4 dv1 = *(const float4*)(dR + 4);
    float4 uv0 = *(const float4*)(uR);
    float4 uv1 = *(const float4*)(uR + 4);
    float4 zv0 = *(const float4*)(zR);
    float4 zv1 = *(const float4*)(zR + 4);
    float4 Bv0 = *(const float4*)(BR);
    float4 Bv1 = *(const float4*)(BR + 4);
    float4 Cv0 = *(const float4*)(CR);
    float4 Cv1 = *(const float4*)(CR + 4);
    float h = 0.f;

    for (int g = 0; g < 256; ++g) {
        int gp = (g + 2 < 256) ? (g + 2) * 4 : 255 * 4;
        float4 dv2 = *(const float4*)(dR + gp);
        float4 uv2 = *(const float4*)(uR + gp);
        float4 zv2 = *(const float4*)(zR + gp);
        float4 Bv2 = *(const float4*)(BR + gp);
        float4 Cv2 = *(const float4*)(CR + gp);

        float dv[4] = {dv0.x, dv0.y, dv0.z, dv0.w};
        float uv[4] = {uv0.x, uv0.y, uv0.z, uv0.w};
        float zv[4] = {zv0.x, zv0.y, zv0.z, zv0.w};
        float Bv[4] = {Bv0.x, Bv0.y, Bv0.z, Bv0.w};
        float Cv[4] = {Cv0.x, Cv0.y, Cv0.z, Cv0.w};
        float ya[4];
        #pragma unroll
        for (int j = 0; j < 4; ++j) {
            float dA = __expf(dv[j] * a);
            h = fmaf(dA, h, dv[j] * uv[j] * Bv[j]);
            float yp = h * Cv[j];
            yp += __shfl_down(yp, 8, 16);
            yp += __shfl_down(yp, 4, 16);
            yp += __shfl_down(yp, 2, 16);
            yp += __shfl_down(yp, 1, 16);
            float z = zv[j];
            ya[j] = (yp + dp * uv[j]) * (z / (1.f + __expf(-z)));
        }
        if (s == 0) {
            *(float4*)(yR + g * 4) = make_float4(ya[0], ya[1], ya[2], ya[3]);
        }
        dv0 = dv1; dv1 = dv2;
        uv0 = uv1; uv1 = uv2;
        zv0 = zv1; zv1 = zv2;
        Bv0 = Bv1; Bv1 = Bv2;
        Cv0 = Cv1; Cv1 = Cv2;
    }
}

// ---------------------------------------------------------------------------
// Sinkhorn half-iterations on la = la0 - R_i - C_j (never materialized).
// ---------------------------------------------------------------------------
__global__ __launch_bounds__(256) void col_lse_part(
    const float* __restrict__ la0, const float* __restrict__ R,
    float2* __restrict__ cpart)
{
    int j = blockIdx.x * 256 + threadIdx.x;
    int ch = blockIdx.y;   // 16 chunks of 64 i's
    int b = blockIdx.z;
    const float* base = la0 + (long long)b * 1024 * 1024 + (long long)ch * 64 * 1024 + j;
    const float* Rb = R + b * 1024 + ch * 64;
    float m = -INFINITY, sum = 0.f;
    for (int i = 0; i < 64; ++i) {
        float x = base[(long long)i * 1024] - Rb[i];
        float nm = fmaxf(m, x);
        sum = sum * expf(m - nm) + expf(x - nm);
        m = nm;
    }
    cpart[(long long)(b * 16 + ch) * 1024 + j] = make_float2(m, sum);
}

__global__ __launch_bounds__(256) void col_comb_k(
    const float2* __restrict__ cpart, float* __restrict__ Cv)
{
    int idx = blockIdx.x * 256 + threadIdx.x;   // b*1024 + j
    int b = idx >> 10, j = idx & 1023;
    float m = -INFINITY, sum = 0.f;
    #pragma unroll
    for (int ch = 0; ch < 16; ++ch) {
        float2 p = cpart[(long long)(b * 16 + ch) * 1024 + j];
        float nm = fmaxf(m, p.x);
        sum = sum * expf(m - nm) + p.y * expf(p.x - nm);
        m = nm;
    }
    Cv[idx] = m + logf(sum);
}

__global__ __launch_bounds__(256) void row_lse_k(
    const float* __restrict__ la0, const float* __restrict__ Cv,
    float* __restrict__ R)
{
    int r = blockIdx.x;
    int b = r >> 10;
    const float* row = la0 + (long long)r * 1024;
    const float* Cb = Cv + b * 1024;
    int tid = threadIdx.x;
    float m = -INFINITY, sum = 0.f;
    #pragma unroll
    for (int k = 0; k < 4; ++k) {
        int j = tid + k * 256;
        float x = row[j] - Cb[j];
        float nm = fmaxf(m, x);
        sum = sum * expf(m - nm) + expf(x - nm);
        m = nm;
    }
    __shared__ float sm[256], ss[256];
    sm[tid] = m; ss[tid] = sum;
    __syncthreads();
    for (int w = 128; w > 0; w >>= 1) {
        if (tid < w) {
            float m2 = sm[tid + w], s2 = ss[tid + w];
            float nm = fmaxf(sm[tid], m2);
            ss[tid] = ss[tid] * expf(sm[tid] - nm) + s2 * expf(m2 - nm);
            sm[tid] = nm;
        }
        __syncthreads();
    }
    if (tid == 0) R[r] = sm[0] + logf(ss[0]);
}

// ---------------------------------------------------------------------------
// Final: argmax(la+gumbel) (first-index ties), log_prob, entropy.
// out layout: tours[16384] | log_probs[16384] | entropies[16384] (all fp32)
// ---------------------------------------------------------------------------
__global__ __launch_bounds__(256) void final_k(
    const float* __restrict__ la0, const float* __restrict__ R,
    const float* __restrict__ Cv, const float* __restrict__ gs,
    float* __restrict__ out)
{
    int r = blockIdx.x;
    int b = r >> 10;
    const float* row = la0 + (long long)r * 1024;
    const float* gr = gs + (long long)r * 1024;
    const float* Cb = Cv + b * 1024;
    float Rvv = R[r];
    int tid = threadIdx.x;
    float bestg = -INFINITY;
    int bestj = 1 << 30;
    float ent = 0.f;
    #pragma unroll
    for (int k = 0; k < 4; ++k) {
        int j = tid + k * 256;
        float la = row[j] - Rvv - Cb[j];
        ent += la * expf(la);
        float g = la + gr[j];
        if (g > bestg || (g == bestg && j < bestj)) { bestg = g; bestj = j; }
    }
    __shared__ float sg[256]; __shared__ int sj[256]; __shared__ float se[256];
    sg[tid] = bestg; sj[tid] = bestj; se[tid] = ent;
    __syncthreads();
    for (int w = 128; w > 0; w >>= 1) {
        if (tid < w) {
            se[tid] += se[tid + w];
            float g2 = sg[tid + w]; int j2 = sj[tid + w];
            if (g2 > sg[tid] || (g2 == sg[tid] && j2 < sj[tid])) {
                sg[tid] = g2; sj[tid] = j2;
            }
        }
        __syncthreads();
    }
    if (tid == 0) {
        int j = sj[0];
        out[r] = (float)j;
        out[16384 + r] = row[j] - Rvv - Cb[j];
        out[32768 + r] = -se[0];
    }
}

// ---------------------------------------------------------------------------
extern "C" void kernel_launch(void* const* d_in, const int* in_sizes, int n_in,
                              void* d_out, int out_size, void* d_ws, size_t ws_size,
                              hipStream_t stream)
{
    const float* graph_emb = (const float*)d_in[0];
    const float* node_emb  = (const float*)d_in[1];
    const float* W_key     = (const float*)d_in[2];
    const float* rms_w     = (const float*)d_in[3];
    const float* W_in      = (const float*)d_in[4];
    const float* conv_w    = (const float*)d_in[5];
    const float* conv_b    = (const float*)d_in[6];
    const float* W_x       = (const float*)d_in[7];
    const float* W_dt      = (const float*)d_in[8];
    const float* b_dt      = (const float*)d_in[9];
    const float* A_log     = (const float*)d_in[10];
    const float* Dp        = (const float*)d_in[11];
    const float* W_out     = (const float*)d_in[12];
    const float* g_sink    = (const float*)d_in[13];
    const float* g_samp    = (const float*)d_in[14];
    float* out = (float*)d_out;

    // Workspace layout (floats). Total = 45,531,136 floats = 182.1 MB.
    float* ws = (float*)d_ws;
    size_t o = 0;
    auto alloc = [&](size_t nf) { float* p = ws + o; o += nf; return p; };
    float* rs    = alloc(ROWS);                    // 16K
    float* dbc   = alloc((size_t)ROWS * 56);       // 0.92M
    float* keys  = alloc((size_t)ROWS * 384);      // 6.29M
    float* R1    = alloc((size_t)ROWS * 768);      // uB -> deltaT -> queries
    float* R2    = alloc((size_t)ROWS * 768);      // uT -> gated yT (in-place); la0 starts here
    float* R3    = alloc((size_t)ROWS * 768);      // zT; la0 spills here
    float* Rv    = alloc(ROWS);
    float* Cvec  = alloc(ROWS);
    float* cpart = alloc((size_t)16 * 16 * 1024 * 2);  // aliased by TBC (disjoint lifetime)
    float* uB      = R1;
    float* deltaT  = R1;    // uB dead after conv
    float* queries = R1;    // deltaT dead after scan
    float* uT      = R2;    // also gated yT (scan writes in-place)
    float* zT      = R3;
    float* la0     = R2;    // R2+R3 span 25.17M >= 16.78M; yT/zT dead by then
    float* TBC     = cpart; // 32*16384 = 524288 = cpart size

    // 1. RMS row scales over virtual ctx
    rms_k<<<dim3(ROWS), 128, 0, stream>>>(graph_emb, node_emb, rs);

    // 2. keys = node_emb @ W_key       (16384 x 384 x 128)
    gemm2_k<0, false, 0, false><<<dim3(3, 128, 1), 256, 0, stream>>>(
        node_emb, 128, 0, W_key, 384, 0, keys, 384, 0,
        ROWS, 384, 128, nullptr, nullptr, nullptr, nullptr, nullptr, nullptr, 0);

    // 3a. uB = rmsnorm(ctx) @ W_in[:, :768]   (16384 x 768 x 384)
    gemm2_k<0, false, 1, false><<<dim3(6, 128, 1), 256, 0, stream>>>(
        nullptr, 0, 0, W_in, 1536, 0, uB, 768, 0,
        ROWS, 768, 384, graph_emb, node_emb, rs, rms_w, nullptr, nullptr, 0);

    // 3b. zT[768][16384] = (rmsnorm(ctx) @ W_in[:, 768:])^T  (transposed store)
    gemm2_k<0, false, 1, true><<<dim3(6, 128, 1), 256, 0, stream>>>(
        nullptr, 0, 0, W_in + 768, 1536, 0, zT, 16384, 0,
        ROWS, 768, 384, graph_emb, node_emb, rs, rms_w, nullptr, nullptr, 0);

    // 4. causal depthwise conv + silu, transposed out: uT[d][b*1024+n]
    conv_t_k<<<dim3(16, 24, 16), 256, 0, stream>>>(uB, conv_w, conv_b, uT);

    // 5. dbc = u @ W_x  (A = uT, K-major)      (16384 x 56 x 768)
    gemm2_k<0, false, 2, false><<<dim3(1, 128, 1), 256, 0, stream>>>(
        uT, 16384, 0, W_x, 56, 0, dbc, 56, 0,
        ROWS, 56, 768, nullptr, nullptr, nullptr, nullptr, nullptr, nullptr, 0);

    // 6. deltaT[768 x 16384] = softplus(W_dt^T @ dbc_dt^T + b_dt[row])
    gemm2_k<5, true, 2, false><<<dim3(128, 6, 1), 256, 0, stream>>>(
        W_dt, 768, 0, dbc, 56, 0, deltaT, 16384, 0,
        768, 16384, 24, nullptr, nullptr, nullptr, nullptr, b_dt, nullptr, 0);

    // 7. pack B/C into TBC[32][16384]
    pack_bc_k<<<dim3(64, 32), 256, 0, stream>>>(dbc, TBC);

    // 8. scan v3 (fused + Dp*u and *silu(z)); gated y written in-place over uT
    scan3_k<<<dim3(48, 16), 256, 0, stream>>>(deltaT, uT, zT, TBC, A_log, Dp);

    // 9. queries = ctx + yGated @ W_out    (16384 x 384 x 768)
    gemm2_k<4, false, 2, false><<<dim3(3, 128, 1), 256, 0, stream>>>(
        uT, 16384, 0, W_out, 384, 0, queries, 384, 0,
        ROWS, 384, 768, graph_emb, node_emb, nullptr, nullptr, nullptr, nullptr, 0);

    // 10. la0 = keys @ queries^T + gumbel_sink  (batched NT, 16 x 1024x1024x384)
    gemm2_k<3, true, 0, false><<<dim3(8, 8, 16), 256, 0, stream>>>(
        keys, 384, (long long)Nn * 384, queries, 384, (long long)Nn * 384,
        la0, 1024, (long long)Nn * Nn,
        1024, 1024, 384, nullptr, nullptr, nullptr, nullptr, nullptr,
        g_sink, (long long)Nn * Nn);

    // 11. Sinkhorn: la = la0 - R_i - C_j, alternate LSE updates
    zero_k<<<dim3(64), 256, 0, stream>>>(Rv, ROWS);
    for (int it = 0; it < 5; ++it) {
        col_lse_part<<<dim3(4, 16, 16), 256, 0, stream>>>(la0, Rv, (float2*)cpart);
        col_comb_k<<<dim3(64), 256, 0, stream>>>((const float2*)cpart, Cvec);
        row_lse_k<<<dim3(ROWS), 256, 0, stream>>>(la0, Cvec, Rv);
    }

    // 12. outputs
    final_k<<<dim3(ROWS), 256, 0, stream>>>(la0, Rv, Cvec, g_samp, out);
}